// Round 2
// 224.151 us; speedup vs baseline: 1.0815x; 1.0815x over previous
//
#include <hip/hip_runtime.h>
#include <math.h>

#define ZB 2
#define NN 4096
#define KNNv 30
#define EDIM 256
#define DM 128
#define CAP2 2048
#define NLV 6

typedef __attribute__((ext_vector_type(8))) short bf16x8;
typedef __attribute__((ext_vector_type(4))) float fx4;

// Eln LDS row stride in bf16 elements: 256 + 8 pad -> A-frag ds_read_b128 is
// 2-way bank aliased (free per m136); 16B-aligned everywhere (264*2=528=33*16).
#define ELN_STR 264

static __device__ inline unsigned short f2bf(float f) {
    unsigned int u = __float_as_uint(f);
    unsigned int r = u + 0x7fffu + ((u >> 16) & 1u);   // RNE
    return (unsigned short)(r >> 16);
}

// ---- fused prep: blocks 0-31 Ca4, 32-63 Wt, 64 bias2 -------------------
__global__ __launch_bounds__(256) void prep_kernel(
    const float* __restrict__ C,
    const float* __restrict__ W, const float* __restrict__ gamma_,
    const float* __restrict__ beta_, const float* __restrict__ bias,
    float4* __restrict__ Ca4, unsigned short* __restrict__ Wt,
    float* __restrict__ bias2)
{
    __shared__ float red[256];
    const int b = blockIdx.x;
    const int t = threadIdx.x;

    if (b < 32) {                                       // dense Ca as float4
        int tid = b * 256 + t;                          // 0..8191
        const float* p = C + (size_t)tid * 12 + 3;      // atom 1
        Ca4[tid] = make_float4(p[0], p[1], p[2], 0.0f);
    } else if (b < 64) {                                // Wt[n][k] = bf16(W[k][n]*g[k])
        int base = (b - 32) * 1024 + t;
        #pragma unroll
        for (int q = 0; q < 4; ++q) {
            int idx = base + q * 256;                   // idx = k*128 + n
            int k = idx >> 7, n = idx & 127;
            Wt[n * 256 + k] = f2bf(W[idx] * gamma_[k]);
        }
    } else {                                            // bias2 = b + beta@W
        const int n = t & 127, half = t >> 7;
        float acc = (half == 0) ? bias[n] : 0.0f;
        const int k0 = half * 128;
        #pragma unroll 8
        for (int k = k0; k < k0 + 128; ++k) acc += beta_[k] * W[k * 128 + n];
        red[t] = acc;
        __syncthreads();
        if (t < 128) bias2[n] = red[t] + red[t + 128];
    }
}

// ---------------- KNN via register keys + threshold ladder --------------
// Selection semantics: slots whose true top-30 entry has sq>=144 emit
// (kidx=i, emask=0) in the reference -> indistinguishable from padding.
// So we only need the exactly-ordered candidates with sq < T where T is the
// smallest ladder threshold holding >= 30 keys (cap 144). No histogram,
// no LDS atomics on the hot path, ~16.6 KB LDS (was 33 KB).
__global__ __launch_bounds__(256) void knn_kernel(
    const float4* __restrict__ Ca4,              // dense (Z*N) x float4
    const unsigned char* __restrict__ node_mask,
    float* __restrict__ out_kidx,
    float* __restrict__ out_emask)
{
    __shared__ unsigned long long buf[CAP2];
    __shared__ unsigned long long sel[KNNv];
    __shared__ unsigned int wred[4 * NLV];
    __shared__ unsigned int s_m;

    const int bi = blockIdx.x;
    const int z  = bi >> 12;
    const int i  = bi & (NN - 1);
    const int t  = threadIdx.x;
    const int lane = t & 63;
    const int wv   = t >> 6;

    if (t == 0) s_m = 0u;

    const float4 me = Ca4[bi];
    const float xi = me.x, yi = me.y, zi = me.z;
    const bool mask_i = node_mask[bi] != 0;
    const float4* Cz = Ca4 + ((size_t)z << 12);

    // distance pass: keys stay in registers; ladder counts via compare-chain
    float sq[16];
    unsigned int c0 = 0, c1 = 0, c2 = 0, c3 = 0, c4 = 0, c5 = 0;
    #pragma unroll
    for (int q = 0; q < 16; ++q) {
        const int j = q * 256 + t;
        float4 p = Cz[j];
        float dx = p.x - xi, dy = p.y - yi, dz = p.z - zi;
        float s = dx * dx + dy * dy + dz * dz;     // identical expr to prev kernel
        if (s == 0.0f || mask_i) s = __builtin_inff();
        sq[q] = s;
        c0 += (s < 4.0f);  c1 += (s < 8.0f);  c2 += (s < 18.0f);
        c3 += (s < 40.0f); c4 += (s < 90.0f); c5 += (s < 144.0f);
    }

    unsigned int cc[NLV] = {c0, c1, c2, c3, c4, c5};
    #pragma unroll
    for (int lv = 0; lv < NLV; ++lv) {
        unsigned int v = cc[lv];
        v += __shfl_xor(v, 1);  v += __shfl_xor(v, 2);  v += __shfl_xor(v, 4);
        v += __shfl_xor(v, 8);  v += __shfl_xor(v, 16); v += __shfl_xor(v, 32);
        if (lane == 0) wred[wv * NLV + lv] = v;
    }
    __syncthreads();

    unsigned int tot[NLV];
    #pragma unroll
    for (int lv = 0; lv < NLV; ++lv)
        tot[lv] = wred[0 * NLV + lv] + wred[1 * NLV + lv]
                + wred[2 * NLV + lv] + wred[3 * NLV + lv];

    float T = 144.0f;                      // smallest threshold with >= KNN keys
    if      (tot[0] >= KNNv) T = 4.0f;
    else if (tot[1] >= KNNv) T = 8.0f;
    else if (tot[2] >= KNNv) T = 18.0f;
    else if (tot[3] >= KNNv) T = 40.0f;
    else if (tot[4] >= KNNv) T = 90.0f;

    // collect candidates (M is exactly tot[chosen], bounded << CAP2)
    #pragma unroll
    for (int q = 0; q < 16; ++q) {
        float s = sq[q];
        if (s < T) {
            unsigned int pos = atomicAdd(&s_m, 1u);
            if (pos < CAP2)
                buf[pos] = ((unsigned long long)__float_as_uint(s) << 32)
                         | (unsigned int)(q * 256 + t);
        }
    }
    __syncthreads();
    unsigned int M = s_m; if (M > CAP2) M = CAP2;

    // rank candidates (broadcast LDS reads, conflict-free)
    for (unsigned int c = t; c < M; c += 256) {
        unsigned long long mev = buf[c];
        unsigned int r = 0;
        for (unsigned int o = 0; o < M; ++o) r += (buf[o] < mev) ? 1u : 0u;
        if (r < KNNv) sel[r] = mev;
    }
    __syncthreads();

    if (t < KNNv) {
        int kv; float emf;
        if ((unsigned int)t < M) {
            unsigned long long p = sel[t];
            unsigned int kbits = (unsigned int)(p >> 32);
            int j = (int)(p & 0xffffffffu);
            float sv = __uint_as_float(kbits);
            bool nb = node_mask[(size_t)z * NN + j] != 0;
            bool em = (!mask_i && !nb) && (sv != 0.0f) && (sv < 144.0f);
            kv = em ? j : i;
            emf = em ? 1.0f : 0.0f;
        } else {                                     // sparse point: pad = self
            kv = i; emf = 0.0f;
        }
        size_t o = (size_t)bi * KNNv + t;
        out_kidx[o]  = (float)kv;
        out_emask[o] = emf;
    }
}

// ---------------- Edges: RBF+LN (bf16) -> MFMA GEMM ---------------------
// Block: 64 edges x 128 cols. Wave w owns cols [32w,32w+32), all 64 edges.
__global__ __launch_bounds__(256) void edge_kernel(
    const float* __restrict__ C,
    const float* __restrict__ kidxf,
    const float* __restrict__ centers,
    const unsigned short* __restrict__ Wt,   // bf16 (128 x 256), gamma folded
    const float* __restrict__ bias2,         // beta@W + b
    float* __restrict__ outE)
{
    __shared__ unsigned short Eln[64 * ELN_STR];   // normalized, bf16
    const int t = threadIdx.x;
    const long g0 = (long)blockIdx.x * 64;

    // ---- phase 1: 4 threads per edge; thread sub handles atom a=sub
    {
        const int e   = t >> 2;
        const int sub = t & 3;
        const long g = g0 + e;
        const int z   = (int)(g / (NN * KNNv));
        const int rem = (int)(g - (long)z * NN * KNNv);
        const int i   = rem / KNNv;
        const int j   = (int)kidxf[g];

        const float* Ci = C + (((size_t)z * NN + i) * 4 + sub) * 3;
        const float ax = Ci[0], ay = Ci[1], az = Ci[2];
        const float* Cjp = C + ((size_t)z * NN + j) * 12;   // 48B-aligned
        float4 q0 = *(const float4*)(Cjp);
        float4 q1 = *(const float4*)(Cjp + 4);
        float4 q2 = *(const float4*)(Cjp + 8);
        const float jx[4] = {q0.x, q0.w, q1.z, q2.y};
        const float jy[4] = {q0.y, q1.x, q1.w, q2.z};
        const float jz[4] = {q0.z, q1.y, q2.x, q2.w};

        float d[4];
        #pragma unroll
        for (int b = 0; b < 4; ++b) {
            float dx = ax - jx[b];
            float dy = ay - jy[b];
            float dz = az - jz[b];
            float s = dx * dx + dy * dy + dz * dz;
            d[b] = s > 0.0f ? sqrtf(s) : 0.0f;
        }
        float cen[16];
        #pragma unroll
        for (int r = 0; r < 16; ++r) cen[r] = centers[r];

        float vals[64];
        float sum = 0.f, sumsq = 0.f;
        #pragma unroll
        for (int b = 0; b < 4; ++b) {
            #pragma unroll
            for (int r = 0; r < 16; ++r) {
                float dd = d[b] - cen[r];
                float v = __expf(dd * dd * -0.64f);
                vals[b * 16 + r] = v;
                sum += v; sumsq += v * v;
            }
        }
        sum   += __shfl_xor(sum, 1);   sum   += __shfl_xor(sum, 2);
        sumsq += __shfl_xor(sumsq, 1); sumsq += __shfl_xor(sumsq, 2);
        const float mu   = sum * (1.0f / 256.0f);
        const float var  = sumsq * (1.0f / 256.0f) - mu * mu;
        const float rstd = rsqrtf(var + 1e-5f);
        // store normalized (gamma/beta folded into Wt/bias2) as bf16
        #pragma unroll
        for (int w = 0; w < 8; ++w) {
            bf16x8 pk;
            #pragma unroll
            for (int v = 0; v < 8; ++v)
                pk[v] = (short)f2bf((vals[w * 8 + v] - mu) * rstd);
            *(bf16x8*)&Eln[e * ELN_STR + sub * 64 + w * 8] = pk;
        }
    }
    __syncthreads();

    // ---- phase 2: MFMA. wave -> 32 cols (2 n-tiles), 4 m-tiles of 16 edges
    {
        const int lane = t & 63;
        const int wv   = t >> 6;
        const int quad = lane >> 4;
        const int l15  = lane & 15;
        const int n0   = wv * 32;

        // B fragments in registers: one W read per wave per block
        bf16x8 Bf[2][8];
        #pragma unroll
        for (int nt = 0; nt < 2; ++nt)
            #pragma unroll
            for (int ks = 0; ks < 8; ++ks)
                Bf[nt][ks] = *(const bf16x8*)(Wt + (size_t)(n0 + nt * 16 + l15) * 256
                                                 + ks * 32 + quad * 8);

        fx4 acc[4][2];
        #pragma unroll
        for (int mt = 0; mt < 4; ++mt)
            #pragma unroll
            for (int nt = 0; nt < 2; ++nt)
                acc[mt][nt] = (fx4){0.f, 0.f, 0.f, 0.f};

        #pragma unroll
        for (int ks = 0; ks < 8; ++ks) {
            bf16x8 Af[4];
            #pragma unroll
            for (int mt = 0; mt < 4; ++mt)
                Af[mt] = *(const bf16x8*)&Eln[(mt * 16 + l15) * ELN_STR + ks * 32 + quad * 8];
            #pragma unroll
            for (int mt = 0; mt < 4; ++mt) {
                acc[mt][0] = __builtin_amdgcn_mfma_f32_16x16x32_bf16(Af[mt], Bf[0][ks], acc[mt][0], 0, 0, 0);
                acc[mt][1] = __builtin_amdgcn_mfma_f32_16x16x32_bf16(Af[mt], Bf[1][ks], acc[mt][1], 0, 0, 0);
            }
        }

        const float bb0 = bias2[n0 + l15];
        const float bb1 = bias2[n0 + 16 + l15];
        #pragma unroll
        for (int mt = 0; mt < 4; ++mt) {
            #pragma unroll
            for (int r = 0; r < 4; ++r) {
                const long row = g0 + mt * 16 + quad * 4 + r;
                float* orow = outE + (size_t)row * DM;
                orow[n0 + l15]      = acc[mt][0][r] + bb0;
                orow[n0 + 16 + l15] = acc[mt][1][r] + bb1;
            }
        }
    }
}

extern "C" void kernel_launch(void* const* d_in, const int* in_sizes, int n_in,
                              void* d_out, int out_size, void* d_ws, size_t ws_size,
                              hipStream_t stream) {
    const float* C          = (const float*)d_in[0];
    const unsigned char* nm = (const unsigned char*)d_in[1];
    const float* centers    = (const float*)d_in[2];
    const float* gamma_     = (const float*)d_in[3];
    const float* beta_      = (const float*)d_in[4];
    const float* W          = (const float*)d_in[5];
    const float* bias       = (const float*)d_in[6];

    float* out = (float*)d_out;
    const size_t nE = (size_t)ZB * NN * KNNv * DM;
    const size_t nK = (size_t)ZB * NN * KNNv;
    float* outE = out;
    float* outK = out + nE;
    float* outM = outK + nK;

    // workspace layout
    unsigned short* Wt    = (unsigned short*)d_ws;                // 64 KiB
    float*          bias2 = (float*)((char*)d_ws + 65536);        // 512 B
    float4*         Ca4   = (float4*)((char*)d_ws + 66048);       // 128 KiB

    prep_kernel<<<65, 256, 0, stream>>>(C, W, gamma_, beta_, bias, Ca4, Wt, bias2);
    knn_kernel<<<ZB * NN, 256, 0, stream>>>(Ca4, nm, outK, outM);
    edge_kernel<<<(int)(nK / 64), 256, 0, stream>>>(C, outK, centers, Wt, bias2, outE);
}

// Round 3
// 222.539 us; speedup vs baseline: 1.0893x; 1.0072x over previous
//
#include <hip/hip_runtime.h>
#include <math.h>

#define ZB 2
#define NN 4096
#define KNNv 30
#define EDIM 256
#define DM 128
#define CAP2 2048
#define NLV 6

typedef __attribute__((ext_vector_type(8))) short bf16x8;
typedef __attribute__((ext_vector_type(4))) float fx4;

// Eln LDS row stride in bf16 elements: 256 + 8 pad -> A-frag ds_read_b128 is
// 2-way bank aliased (free per m136); 16B-aligned everywhere (264*2=528=33*16).
#define ELN_STR 264

static __device__ inline unsigned short f2bf(float f) {
    unsigned int u = __float_as_uint(f);
    unsigned int r = u + 0x7fffu + ((u >> 16) & 1u);   // RNE
    return (unsigned short)(r >> 16);
}

// ---- fused prep: blocks 0-31 Ca4, 32-63 Wt, 64 bias2 -------------------
__global__ __launch_bounds__(256) void prep_kernel(
    const float* __restrict__ C,
    const float* __restrict__ W, const float* __restrict__ gamma_,
    const float* __restrict__ beta_, const float* __restrict__ bias,
    float4* __restrict__ Ca4, unsigned short* __restrict__ Wt,
    float* __restrict__ bias2)
{
    __shared__ float red[256];
    const int b = blockIdx.x;
    const int t = threadIdx.x;

    if (b < 32) {                                       // dense Ca as float4
        int tid = b * 256 + t;                          // 0..8191
        const float* p = C + (size_t)tid * 12 + 3;      // atom 1
        Ca4[tid] = make_float4(p[0], p[1], p[2], 0.0f);
    } else if (b < 64) {                                // Wt[n][k] = bf16(W[k][n]*g[k])
        int base = (b - 32) * 1024 + t;
        #pragma unroll
        for (int q = 0; q < 4; ++q) {
            int idx = base + q * 256;                   // idx = k*128 + n
            int k = idx >> 7, n = idx & 127;
            Wt[n * 256 + k] = f2bf(W[idx] * gamma_[k]);
        }
    } else {                                            // bias2 = b + beta@W
        const int n = t & 127, half = t >> 7;
        float acc = (half == 0) ? bias[n] : 0.0f;
        const int k0 = half * 128;
        #pragma unroll 8
        for (int k = k0; k < k0 + 128; ++k) acc += beta_[k] * W[k * 128 + n];
        red[t] = acc;
        __syncthreads();
        if (t < 128) bias2[n] = red[t] + red[t + 128];
    }
}

// ---------------- KNN: 2 queries per block, shared sweep ----------------
// One 4096-point sweep serves two query nodes (2b, 2b+1) — halves the L2
// read traffic that dominated knn. Ladder select semantics identical to the
// verified round-1 kernel: smallest threshold in {4,8,18,40,90,144} holding
// >= 30 keys; slots whose true top-30 entry has sq>=144 are output-
// indistinguishable from self-padding (kidx=i, emask=0) per reference.
__global__ __launch_bounds__(256) void knn_kernel(
    const float4* __restrict__ Ca4,              // dense (Z*N) x float4
    const unsigned char* __restrict__ node_mask,
    float* __restrict__ out_kidx,
    float* __restrict__ out_emask)
{
    __shared__ unsigned long long buf[CAP2];
    __shared__ unsigned long long sel[KNNv];
    __shared__ unsigned int wred[4 * 2 * NLV];
    __shared__ unsigned int s_m;

    const int bp  = blockIdx.x;                  // pair index
    const int bi0 = bp * 2;                      // query 0 node (global)
    const int bi1 = bi0 + 1;                     // query 1 node (same z)
    const int z   = bi0 >> 12;
    const int i0  = bi0 & (NN - 1);
    const int i1  = bi1 & (NN - 1);
    const int t   = threadIdx.x;
    const int lane = t & 63;
    const int wv   = t >> 6;

    if (t == 0) s_m = 0u;

    const float4 me0 = Ca4[bi0];
    const float4 me1 = Ca4[bi1];
    const bool mask0 = node_mask[bi0] != 0;
    const bool mask1 = node_mask[bi1] != 0;
    const float4* Cz = Ca4 + ((size_t)z << 12);

    // shared sweep: distances for both queries stay in registers
    float sq0[16], sq1[16];
    unsigned int a0 = 0, a1 = 0, a2 = 0, a3 = 0, a4 = 0, a5 = 0;
    unsigned int b0 = 0, b1 = 0, b2 = 0, b3 = 0, b4 = 0, b5 = 0;
    #pragma unroll
    for (int q = 0; q < 16; ++q) {
        const int j = q * 256 + t;
        float4 p = Cz[j];
        float dx0 = p.x - me0.x, dy0 = p.y - me0.y, dz0 = p.z - me0.z;
        float s0 = dx0 * dx0 + dy0 * dy0 + dz0 * dz0;
        float dx1 = p.x - me1.x, dy1 = p.y - me1.y, dz1 = p.z - me1.z;
        float s1 = dx1 * dx1 + dy1 * dy1 + dz1 * dz1;
        if (s0 == 0.0f || mask0) s0 = __builtin_inff();
        if (s1 == 0.0f || mask1) s1 = __builtin_inff();
        sq0[q] = s0;
        sq1[q] = s1;
        a0 += (s0 < 4.0f);  a1 += (s0 < 8.0f);  a2 += (s0 < 18.0f);
        a3 += (s0 < 40.0f); a4 += (s0 < 90.0f); a5 += (s0 < 144.0f);
        b0 += (s1 < 4.0f);  b1 += (s1 < 8.0f);  b2 += (s1 < 18.0f);
        b3 += (s1 < 40.0f); b4 += (s1 < 90.0f); b5 += (s1 < 144.0f);
    }

    unsigned int cc[2 * NLV] = {a0, a1, a2, a3, a4, a5, b0, b1, b2, b3, b4, b5};
    #pragma unroll
    for (int lv = 0; lv < 2 * NLV; ++lv) {
        unsigned int v = cc[lv];
        v += __shfl_xor(v, 1);  v += __shfl_xor(v, 2);  v += __shfl_xor(v, 4);
        v += __shfl_xor(v, 8);  v += __shfl_xor(v, 16); v += __shfl_xor(v, 32);
        if (lane == 0) wred[wv * 2 * NLV + lv] = v;
    }
    __syncthreads();                             // also covers s_m init

    unsigned int tot0[NLV], tot1[NLV];
    #pragma unroll
    for (int lv = 0; lv < NLV; ++lv) {
        tot0[lv] = wred[0 * 2 * NLV + lv] + wred[1 * 2 * NLV + lv]
                 + wred[2 * 2 * NLV + lv] + wred[3 * 2 * NLV + lv];
        tot1[lv] = wred[0 * 2 * NLV + NLV + lv] + wred[1 * 2 * NLV + NLV + lv]
                 + wred[2 * 2 * NLV + NLV + lv] + wred[3 * 2 * NLV + NLV + lv];
    }

    float T0 = 144.0f;
    if      (tot0[0] >= KNNv) T0 = 4.0f;
    else if (tot0[1] >= KNNv) T0 = 8.0f;
    else if (tot0[2] >= KNNv) T0 = 18.0f;
    else if (tot0[3] >= KNNv) T0 = 40.0f;
    else if (tot0[4] >= KNNv) T0 = 90.0f;
    float T1 = 144.0f;
    if      (tot1[0] >= KNNv) T1 = 4.0f;
    else if (tot1[1] >= KNNv) T1 = 8.0f;
    else if (tot1[2] >= KNNv) T1 = 18.0f;
    else if (tot1[3] >= KNNv) T1 = 40.0f;
    else if (tot1[4] >= KNNv) T1 = 90.0f;

    // -------- query 0: collect -> rank -> write --------
    #pragma unroll
    for (int q = 0; q < 16; ++q) {
        float s = sq0[q];
        if (s < T0) {
            unsigned int pos = atomicAdd(&s_m, 1u);
            if (pos < CAP2)
                buf[pos] = ((unsigned long long)__float_as_uint(s) << 32)
                         | (unsigned int)(q * 256 + t);
        }
    }
    __syncthreads();
    unsigned int M0 = s_m; if (M0 > CAP2) M0 = CAP2;

    for (unsigned int c = t; c < M0; c += 256) {
        unsigned long long mev = buf[c];
        unsigned int r = 0;
        for (unsigned int o = 0; o < M0; ++o) r += (buf[o] < mev) ? 1u : 0u;
        if (r < KNNv) sel[r] = mev;
    }
    __syncthreads();

    if (t < KNNv) {
        int kv; float emf;
        if ((unsigned int)t < M0) {
            unsigned long long p = sel[t];
            int j = (int)(p & 0xffffffffu);
            float sv = __uint_as_float((unsigned int)(p >> 32));
            bool nb = node_mask[(size_t)z * NN + j] != 0;
            bool em = (!mask0 && !nb) && (sv != 0.0f) && (sv < 144.0f);
            kv = em ? j : i0;
            emf = em ? 1.0f : 0.0f;
        } else { kv = i0; emf = 0.0f; }
        size_t o = (size_t)bi0 * KNNv + t;
        out_kidx[o]  = (float)kv;
        out_emask[o] = emf;
    }
    if (t == 0) s_m = 0u;                        // sel reads above done by writers
    __syncthreads();                             // buf/sel safe to overwrite

    // -------- query 1: collect -> rank -> write --------
    #pragma unroll
    for (int q = 0; q < 16; ++q) {
        float s = sq1[q];
        if (s < T1) {
            unsigned int pos = atomicAdd(&s_m, 1u);
            if (pos < CAP2)
                buf[pos] = ((unsigned long long)__float_as_uint(s) << 32)
                         | (unsigned int)(q * 256 + t);
        }
    }
    __syncthreads();
    unsigned int M1 = s_m; if (M1 > CAP2) M1 = CAP2;

    for (unsigned int c = t; c < M1; c += 256) {
        unsigned long long mev = buf[c];
        unsigned int r = 0;
        for (unsigned int o = 0; o < M1; ++o) r += (buf[o] < mev) ? 1u : 0u;
        if (r < KNNv) sel[r] = mev;
    }
    __syncthreads();

    if (t < KNNv) {
        int kv; float emf;
        if ((unsigned int)t < M1) {
            unsigned long long p = sel[t];
            int j = (int)(p & 0xffffffffu);
            float sv = __uint_as_float((unsigned int)(p >> 32));
            bool nb = node_mask[(size_t)z * NN + j] != 0;
            bool em = (!mask1 && !nb) && (sv != 0.0f) && (sv < 144.0f);
            kv = em ? j : i1;
            emf = em ? 1.0f : 0.0f;
        } else { kv = i1; emf = 0.0f; }
        size_t o = (size_t)bi1 * KNNv + t;
        out_kidx[o]  = (float)kv;
        out_emask[o] = emf;
    }
}

// ---------------- Edges: RBF+LN (bf16) -> MFMA GEMM ---------------------
// Block: 64 edges x 128 cols. Wave w owns cols [32w,32w+32), all 64 edges.
__global__ __launch_bounds__(256) void edge_kernel(
    const float* __restrict__ C,
    const float* __restrict__ kidxf,
    const float* __restrict__ centers,
    const unsigned short* __restrict__ Wt,   // bf16 (128 x 256), gamma folded
    const float* __restrict__ bias2,         // beta@W + b
    float* __restrict__ outE)
{
    __shared__ unsigned short Eln[64 * ELN_STR];   // normalized, bf16
    const int t = threadIdx.x;
    const int g0 = (int)blockIdx.x * 64;           // max 245,760: 32-bit safe

    // ---- phase 1: 4 threads per edge; thread sub handles atom a=sub
    {
        const int e   = t >> 2;
        const int sub = t & 3;
        const int g   = g0 + e;
        const int z   = g / (NN * KNNv);           // const divisor -> magic mul
        const int rem = g - z * (NN * KNNv);
        const int i   = rem / KNNv;                // const divisor -> magic mul
        const int j   = (int)kidxf[g];

        const float* Ci = C + (((size_t)z * NN + i) * 4 + sub) * 3;
        const float ax = Ci[0], ay = Ci[1], az = Ci[2];
        const float* Cjp = C + ((size_t)z * NN + j) * 12;   // 48B-aligned
        float4 q0 = *(const float4*)(Cjp);
        float4 q1 = *(const float4*)(Cjp + 4);
        float4 q2 = *(const float4*)(Cjp + 8);
        const float jx[4] = {q0.x, q0.w, q1.z, q2.y};
        const float jy[4] = {q0.y, q1.x, q1.w, q2.z};
        const float jz[4] = {q0.z, q1.y, q2.x, q2.w};

        float d[4];
        #pragma unroll
        for (int b = 0; b < 4; ++b) {
            float dx = ax - jx[b];
            float dy = ay - jy[b];
            float dz = az - jz[b];
            float s = dx * dx + dy * dy + dz * dz;
            d[b] = s > 0.0f ? sqrtf(s) : 0.0f;
        }
        float cen[16];
        #pragma unroll
        for (int r = 0; r < 16; ++r) cen[r] = centers[r];

        float vals[64];
        float sum = 0.f, sumsq = 0.f;
        #pragma unroll
        for (int b = 0; b < 4; ++b) {
            #pragma unroll
            for (int r = 0; r < 16; ++r) {
                float dd = d[b] - cen[r];
                float v = __expf(dd * dd * -0.64f);
                vals[b * 16 + r] = v;
                sum += v; sumsq += v * v;
            }
        }
        sum   += __shfl_xor(sum, 1);   sum   += __shfl_xor(sum, 2);
        sumsq += __shfl_xor(sumsq, 1); sumsq += __shfl_xor(sumsq, 2);
        const float mu   = sum * (1.0f / 256.0f);
        const float var  = sumsq * (1.0f / 256.0f) - mu * mu;
        const float rstd = rsqrtf(var + 1e-5f);
        // store normalized (gamma/beta folded into Wt/bias2) as bf16
        #pragma unroll
        for (int w = 0; w < 8; ++w) {
            bf16x8 pk;
            #pragma unroll
            for (int v = 0; v < 8; ++v)
                pk[v] = (short)f2bf((vals[w * 8 + v] - mu) * rstd);
            *(bf16x8*)&Eln[e * ELN_STR + sub * 64 + w * 8] = pk;
        }
    }
    __syncthreads();

    // ---- phase 2: MFMA. wave -> 32 cols (2 n-tiles), 4 m-tiles of 16 edges
    {
        const int lane = t & 63;
        const int wv   = t >> 6;
        const int quad = lane >> 4;
        const int l15  = lane & 15;
        const int n0   = wv * 32;

        // B fragments in registers: one W read per wave per block
        bf16x8 Bf[2][8];
        #pragma unroll
        for (int nt = 0; nt < 2; ++nt)
            #pragma unroll
            for (int ks = 0; ks < 8; ++ks)
                Bf[nt][ks] = *(const bf16x8*)(Wt + (size_t)(n0 + nt * 16 + l15) * 256
                                                 + ks * 32 + quad * 8);

        fx4 acc[4][2];
        #pragma unroll
        for (int mt = 0; mt < 4; ++mt)
            #pragma unroll
            for (int nt = 0; nt < 2; ++nt)
                acc[mt][nt] = (fx4){0.f, 0.f, 0.f, 0.f};

        #pragma unroll
        for (int ks = 0; ks < 8; ++ks) {
            bf16x8 Af[4];
            #pragma unroll
            for (int mt = 0; mt < 4; ++mt)
                Af[mt] = *(const bf16x8*)&Eln[(mt * 16 + l15) * ELN_STR + ks * 32 + quad * 8];
            #pragma unroll
            for (int mt = 0; mt < 4; ++mt) {
                acc[mt][0] = __builtin_amdgcn_mfma_f32_16x16x32_bf16(Af[mt], Bf[0][ks], acc[mt][0], 0, 0, 0);
                acc[mt][1] = __builtin_amdgcn_mfma_f32_16x16x32_bf16(Af[mt], Bf[1][ks], acc[mt][1], 0, 0, 0);
            }
        }

        const float bb0 = bias2[n0 + l15];
        const float bb1 = bias2[n0 + 16 + l15];
        #pragma unroll
        for (int mt = 0; mt < 4; ++mt) {
            #pragma unroll
            for (int r = 0; r < 4; ++r) {
                const int row = g0 + mt * 16 + quad * 4 + r;
                float* orow = outE + (size_t)row * DM;
                __builtin_nontemporal_store(acc[mt][0][r] + bb0, orow + n0 + l15);
                __builtin_nontemporal_store(acc[mt][1][r] + bb1, orow + n0 + 16 + l15);
            }
        }
    }
}

extern "C" void kernel_launch(void* const* d_in, const int* in_sizes, int n_in,
                              void* d_out, int out_size, void* d_ws, size_t ws_size,
                              hipStream_t stream) {
    const float* C          = (const float*)d_in[0];
    const unsigned char* nm = (const unsigned char*)d_in[1];
    const float* centers    = (const float*)d_in[2];
    const float* gamma_     = (const float*)d_in[3];
    const float* beta_      = (const float*)d_in[4];
    const float* W          = (const float*)d_in[5];
    const float* bias       = (const float*)d_in[6];

    float* out = (float*)d_out;
    const size_t nE = (size_t)ZB * NN * KNNv * DM;
    const size_t nK = (size_t)ZB * NN * KNNv;
    float* outE = out;
    float* outK = out + nE;
    float* outM = outK + nK;

    // workspace layout
    unsigned short* Wt    = (unsigned short*)d_ws;                // 64 KiB
    float*          bias2 = (float*)((char*)d_ws + 65536);        // 512 B
    float4*         Ca4   = (float4*)((char*)d_ws + 66048);       // 128 KiB

    prep_kernel<<<65, 256, 0, stream>>>(C, W, gamma_, beta_, bias, Ca4, Wt, bias2);
    knn_kernel<<<ZB * NN / 2, 256, 0, stream>>>(Ca4, nm, outK, outM);
    edge_kernel<<<(int)(nK / 64), 256, 0, stream>>>(C, outK, centers, Wt, bias2, outE);
}